// Round 16
// baseline (95.796 us; speedup 1.0000x reference)
//
#include <hip/hip_runtime.h>

#define NN 131072
#define NE 1048576
#define DD 64
#define NG 32
#define NPG 4096
#define NB 512      // buckets (c>>8), 256 nodes each
#define CAPB 2560   // padded bucket capacity (E=2048, +11 sigma)

typedef __attribute__((ext_vector_type(2))) float f32x2;

// ---- bucket scatter: 256 blocks x 4096 edges (16/thread); LDS-aggregated reservation ----
extern "C" __global__ __launch_bounds__(256) void k_bscatter(
    const int* __restrict__ row, const int* __restrict__ col, int* __restrict__ bcursor,
    int* __restrict__ ebuf) {
  __shared__ int sh[NB];   // local histogram
  __shared__ int sb[NB];   // global base per bin
  int t = threadIdx.x;
  sh[t] = 0; sh[t + 256] = 0;
  __syncthreads();
  int base = blockIdx.x * 4096 + t * 16;
  const int4* c4 = reinterpret_cast<const int4*>(col + base);
  int4 cA = c4[0], cB = c4[1], cC = c4[2], cD = c4[3];
  int cols[16] = {cA.x, cA.y, cA.z, cA.w, cB.x, cB.y, cB.z, cB.w,
                  cC.x, cC.y, cC.z, cC.w, cD.x, cD.y, cD.z, cD.w};
  int lr[16];
#pragma unroll
  for (int k = 0; k < 16; ++k) lr[k] = atomicAdd(&sh[cols[k] >> 8], 1);
  __syncthreads();
  int h0 = sh[t];
  sb[t] = t * CAPB + (h0 ? atomicAdd(&bcursor[t], h0) : 0);
  int h1 = sh[t + 256];
  sb[t + 256] = (t + 256) * CAPB + (h1 ? atomicAdd(&bcursor[t + 256], h1) : 0);
  __syncthreads();
  const int4* r4 = reinterpret_cast<const int4*>(row + base);
  int4 rA = r4[0], rB = r4[1], rC = r4[2], rD = r4[3];
  int rows[16] = {rA.x, rA.y, rA.z, rA.w, rB.x, rB.y, rB.z, rB.w,
                  rC.x, rC.y, rC.z, rC.w, rD.x, rD.y, rD.z, rD.w};
#pragma unroll
  for (int k = 0; k < 16; ++k) {
    int key = cols[k] >> 8;
    int pos = sb[key] + lr[k];
    if (pos < (key + 1) * CAPB)  // guard never hits
      ebuf[pos] = (rows[k] << 8) | (cols[k] & 255);
  }
}

// ---- per-bucket: LDS-cached edges; histogram -> cnt/dis/starts -> LDS-cursor scatter ----
extern "C" __global__ __launch_bounds__(256) void k_blocal(
    const int* __restrict__ ebuf, const int* __restrict__ bcursor, int* __restrict__ cnt,
    float* __restrict__ dis, int* __restrict__ starts, int* __restrict__ nbr) {
  __shared__ int led[CAPB];  // cached bucket edges, 10 KB
  __shared__ int sh[256];    // per-node histogram
  __shared__ int sx[256];    // scan workspace, then cursor
  int b = blockIdx.x, t = threadIdx.x;
  int bs = b * CAPB;
  int n_e = bcursor[b];
  if (n_e > CAPB) n_e = CAPB;
  sh[t] = 0;
  __syncthreads();
  for (int i = t; i < n_e; i += 256) {
    int ed = ebuf[bs + i];
    led[i] = ed;
    atomicAdd(&sh[ed & 255], 1);
  }
  __syncthreads();
  int v = sh[t];
  sx[t] = v;
  __syncthreads();
  for (int off = 1; off < 256; off <<= 1) {
    int u = (t >= off) ? sx[t - off] : 0;
    __syncthreads();
    sx[t] += u;
    __syncthreads();
  }
  int st = bs + sx[t] - v;  // global start (padded layout)
  int node = b * 256 + t;
  cnt[node] = v;
  dis[node] = rsqrtf((float)v + 1.0f);
  starts[node] = st;
  sx[t] = st;  // becomes cursor
  __syncthreads();
  for (int i = t; i < n_e; i += 256) {
    int ed = led[i];
    int pos = atomicAdd(&sx[ed & 255], 1);
    nbr[pos] = ed >> 8;
  }
}

// ---- GEMM1: h1 = fp8(x @ W1), 4 rows/thread x 16 cols/thread, bounded unroll ----
extern "C" __global__ __launch_bounds__(256) void k_gemm1s(
    const float* __restrict__ x, const float* __restrict__ W1,
    unsigned char* __restrict__ h1f, const float* __restrict__ b2, float* __restrict__ out) {
  __shared__ float4 wl[DD * 16];  // W1 as [k][j4], 16 KB
  int t = threadIdx.x;
  if (blockIdx.x == 0 && t < NG * 3) out[t] = b2[t % 3];
  for (int i = t; i < DD * 16; i += 256) wl[i] = reinterpret_cast<const float4*>(W1)[i];
  __syncthreads();
  int jc = t & 3;   // column chunk: cols [16*jc, 16*jc+16)
  int rg = t >> 2;  // row group 0..63, 4 rows each
  size_t rbase = (size_t)blockIdx.x * 256 + (size_t)rg * 4;
  const float4* xp = reinterpret_cast<const float4*>(x + rbase * DD);
  float4 acc[4][4];
#pragma unroll
  for (int r = 0; r < 4; ++r)
#pragma unroll
    for (int j = 0; j < 4; ++j) acc[r][j] = make_float4(0.f, 0.f, 0.f, 0.f);
#pragma unroll 2
  for (int kk = 0; kk < 16; ++kk) {
    float4 a0 = xp[kk];       // streamed rows
    float4 a1 = xp[16 + kk];
    float4 a2 = xp[32 + kk];
    float4 a3 = xp[48 + kk];
#pragma unroll
    for (int j = 0; j < 4; ++j) {
      float4 w0 = wl[(4 * kk + 0) * 16 + jc * 4 + j];
      float4 w1 = wl[(4 * kk + 1) * 16 + jc * 4 + j];
      float4 w2 = wl[(4 * kk + 2) * 16 + jc * 4 + j];
      float4 w3 = wl[(4 * kk + 3) * 16 + jc * 4 + j];
      acc[0][j].x += a0.x * w0.x + a0.y * w1.x + a0.z * w2.x + a0.w * w3.x;
      acc[0][j].y += a0.x * w0.y + a0.y * w1.y + a0.z * w2.y + a0.w * w3.y;
      acc[0][j].z += a0.x * w0.z + a0.y * w1.z + a0.z * w2.z + a0.w * w3.z;
      acc[0][j].w += a0.x * w0.w + a0.y * w1.w + a0.z * w2.w + a0.w * w3.w;
      acc[1][j].x += a1.x * w0.x + a1.y * w1.x + a1.z * w2.x + a1.w * w3.x;
      acc[1][j].y += a1.x * w0.y + a1.y * w1.y + a1.z * w2.y + a1.w * w3.y;
      acc[1][j].z += a1.x * w0.z + a1.y * w1.z + a1.z * w2.z + a1.w * w3.z;
      acc[1][j].w += a1.x * w0.w + a1.y * w1.w + a1.z * w2.w + a1.w * w3.w;
      acc[2][j].x += a2.x * w0.x + a2.y * w1.x + a2.z * w2.x + a2.w * w3.x;
      acc[2][j].y += a2.x * w0.y + a2.y * w1.y + a2.z * w2.y + a2.w * w3.y;
      acc[2][j].z += a2.x * w0.z + a2.y * w1.z + a2.z * w2.z + a2.w * w3.z;
      acc[2][j].w += a2.x * w0.w + a2.y * w1.w + a2.z * w2.w + a2.w * w3.w;
      acc[3][j].x += a3.x * w0.x + a3.y * w1.x + a3.z * w2.x + a3.w * w3.x;
      acc[3][j].y += a3.x * w0.y + a3.y * w1.y + a3.z * w2.y + a3.w * w3.y;
      acc[3][j].z += a3.x * w0.z + a3.y * w1.z + a3.z * w2.z + a3.w * w3.z;
      acc[3][j].w += a3.x * w0.w + a3.y * w1.w + a3.z * w2.w + a3.w * w3.w;
    }
  }
#pragma unroll
  for (int r = 0; r < 4; ++r) {
    unsigned int d[4];
#pragma unroll
    for (int j = 0; j < 4; ++j) {
      float4 a = acc[r][j];
      int dj = __builtin_amdgcn_cvt_pk_fp8_f32(a.x, a.y, 0, false);
      dj = __builtin_amdgcn_cvt_pk_fp8_f32(a.z, a.w, dj, true);
      d[j] = (unsigned int)dj;
    }
    *reinterpret_cast<uint4*>(h1f + (rbase + r) * 64 + jc * 16) =
        make_uint4(d[0], d[1], d[2], d[3]);
  }
}

// ---- fused agg1: 4 nodes/wave, weighted fp8 gather (w staged with nbr), ILP 8 ----
extern "C" __global__ __launch_bounds__(256) void k_agg1f(
    const unsigned char* __restrict__ h1f, const int* __restrict__ starts,
    const int* __restrict__ cnt, const int* __restrict__ nbr, const float* __restrict__ dis,
    const float* __restrict__ b1, const float* __restrict__ W2, float4* __restrict__ h2) {
  __shared__ int2 sed[4][4][16];  // per wave, per node-group: (nbr, w); 2 KB
  int lane = threadIdx.x & 63;
  int wid = threadIdx.x >> 6;
  int g = lane >> 4;   // node group within wave
  int sl = lane & 15;  // slot index; also owns dims [4sl, 4sl+4)
  int node = blockIdx.x * 16 + wid * 4 + g;
  int start = starts[node];
  int deg = cnt[node];
  float dc = dis[node];
  // stage 16 slots: edges (w=dis[nb]*dc), self at slot deg (w=dc^2), pads w=0
  int2 s = make_int2(node, 0);
  if (sl < deg) {
    int nb = nbr[start + sl];
    s = make_int2(nb, __float_as_int(dis[nb] * dc));
  } else if (sl == deg) {
    s = make_int2(node, __float_as_int(dc * dc));
  }
  sed[wid][g][sl] = s;
  int m = (deg < 16) ? (deg + 1) : 16;
  int mw = max(m, __shfl_xor(m, 16));  // max over the 4 groups of this wave
  mw = max(mw, __shfl_xor(mw, 32));
  int mw8 = (mw + 7) & ~7;  // 8 or 16; all 16 slots initialized, pads are w=0
  asm volatile("s_waitcnt lgkmcnt(0)" ::: "memory");  // sed is wave-private
  __builtin_amdgcn_sched_barrier(0);
  const unsigned int* h1u = reinterpret_cast<const unsigned int*>(h1f);  // row = 16 dwords
  const int2* sp = sed[wid][g];
  float a0 = 0.f, a1 = 0.f, a2 = 0.f, a3 = 0.f;
  for (int e = 0; e < mw8; e += 8) {  // 8 independent gather chains; pads add zero
    int2 e0 = sp[e + 0], e1 = sp[e + 1], e2 = sp[e + 2], e3 = sp[e + 3];
    int2 e4 = sp[e + 4], e5 = sp[e + 5], e6 = sp[e + 6], e7 = sp[e + 7];
    unsigned int u0 = h1u[(size_t)e0.x * 16 + sl];
    unsigned int u1 = h1u[(size_t)e1.x * 16 + sl];
    unsigned int u2 = h1u[(size_t)e2.x * 16 + sl];
    unsigned int u3 = h1u[(size_t)e3.x * 16 + sl];
    unsigned int u4 = h1u[(size_t)e4.x * 16 + sl];
    unsigned int u5 = h1u[(size_t)e5.x * 16 + sl];
    unsigned int u6 = h1u[(size_t)e6.x * 16 + sl];
    unsigned int u7 = h1u[(size_t)e7.x * 16 + sl];
    float w0 = __int_as_float(e0.y), w1 = __int_as_float(e1.y);
    float w2 = __int_as_float(e2.y), w3 = __int_as_float(e3.y);
    float w4 = __int_as_float(e4.y), w5 = __int_as_float(e5.y);
    float w6 = __int_as_float(e6.y), w7 = __int_as_float(e7.y);
    f32x2 p0 = __builtin_amdgcn_cvt_pk_f32_fp8(u0, false);
    f32x2 q0 = __builtin_amdgcn_cvt_pk_f32_fp8(u0, true);
    f32x2 p1 = __builtin_amdgcn_cvt_pk_f32_fp8(u1, false);
    f32x2 q1 = __builtin_amdgcn_cvt_pk_f32_fp8(u1, true);
    f32x2 p2 = __builtin_amdgcn_cvt_pk_f32_fp8(u2, false);
    f32x2 q2 = __builtin_amdgcn_cvt_pk_f32_fp8(u2, true);
    f32x2 p3 = __builtin_amdgcn_cvt_pk_f32_fp8(u3, false);
    f32x2 q3 = __builtin_amdgcn_cvt_pk_f32_fp8(u3, true);
    f32x2 p4 = __builtin_amdgcn_cvt_pk_f32_fp8(u4, false);
    f32x2 q4 = __builtin_amdgcn_cvt_pk_f32_fp8(u4, true);
    f32x2 p5 = __builtin_amdgcn_cvt_pk_f32_fp8(u5, false);
    f32x2 q5 = __builtin_amdgcn_cvt_pk_f32_fp8(u5, true);
    f32x2 p6 = __builtin_amdgcn_cvt_pk_f32_fp8(u6, false);
    f32x2 q6 = __builtin_amdgcn_cvt_pk_f32_fp8(u6, true);
    f32x2 p7 = __builtin_amdgcn_cvt_pk_f32_fp8(u7, false);
    f32x2 q7 = __builtin_amdgcn_cvt_pk_f32_fp8(u7, true);
    a0 = fmaf(w0, p0.x, a0); a1 = fmaf(w0, p0.y, a1); a2 = fmaf(w0, q0.x, a2); a3 = fmaf(w0, q0.y, a3);
    a0 = fmaf(w1, p1.x, a0); a1 = fmaf(w1, p1.y, a1); a2 = fmaf(w1, q1.x, a2); a3 = fmaf(w1, q1.y, a3);
    a0 = fmaf(w2, p2.x, a0); a1 = fmaf(w2, p2.y, a1); a2 = fmaf(w2, q2.x, a2); a3 = fmaf(w2, q2.y, a3);
    a0 = fmaf(w3, p3.x, a0); a1 = fmaf(w3, p3.y, a1); a2 = fmaf(w3, q3.x, a2); a3 = fmaf(w3, q3.y, a3);
    a0 = fmaf(w4, p4.x, a0); a1 = fmaf(w4, p4.y, a1); a2 = fmaf(w4, q4.x, a2); a3 = fmaf(w4, q4.y, a3);
    a0 = fmaf(w5, p5.x, a0); a1 = fmaf(w5, p5.y, a1); a2 = fmaf(w5, q5.x, a2); a3 = fmaf(w5, q5.y, a3);
    a0 = fmaf(w6, p6.x, a0); a1 = fmaf(w6, p6.y, a1); a2 = fmaf(w6, q6.x, a2); a3 = fmaf(w6, q6.y, a3);
    a0 = fmaf(w7, p7.x, a0); a1 = fmaf(w7, p7.y, a1); a2 = fmaf(w7, q7.x, a2); a3 = fmaf(w7, q7.y, a3);
  }
  if (deg >= 16) {  // rare tail (~0.4% of nodes): remaining edges + self
    for (int eo = 16; eo < deg; ++eo) {
      int r = nbr[start + eo];
      float q = dis[r] * dc;
      unsigned int u = h1u[(size_t)r * 16 + sl];
      f32x2 p = __builtin_amdgcn_cvt_pk_f32_fp8(u, false);
      f32x2 qq = __builtin_amdgcn_cvt_pk_f32_fp8(u, true);
      a0 = fmaf(q, p.x, a0); a1 = fmaf(q, p.y, a1);
      a2 = fmaf(q, qq.x, a2); a3 = fmaf(q, qq.y, a3);
    }
    float q = dc * dc;
    unsigned int u = h1u[(size_t)node * 16 + sl];
    f32x2 p = __builtin_amdgcn_cvt_pk_f32_fp8(u, false);
    f32x2 qq = __builtin_amdgcn_cvt_pk_f32_fp8(u, true);
    a0 = fmaf(q, p.x, a0); a1 = fmaf(q, p.y, a1);
    a2 = fmaf(q, qq.x, a2); a3 = fmaf(q, qq.y, a3);
  }
  // layer2: z = relu(a + b1); store h2s = dc * (z @ W2), dis in .w
  float4 bb = *reinterpret_cast<const float4*>(b1 + 4 * sl);
  float z0 = fmaxf(a0 + bb.x, 0.f);
  float z1 = fmaxf(a1 + bb.y, 0.f);
  float z2 = fmaxf(a2 + bb.z, 0.f);
  float z3 = fmaxf(a3 + bb.w, 0.f);
  const float4* wp = reinterpret_cast<const float4*>(W2 + 12 * sl);
  float4 wA = wp[0];  // W2[4sl][0..2], W2[4sl+1][0]
  float4 wB = wp[1];  // W2[4sl+1][1..2], W2[4sl+2][0..1]
  float4 wC = wp[2];  // W2[4sl+2][2], W2[4sl+3][0..2]
  float v0 = z0 * wA.x + z1 * wA.w + z2 * wB.z + z3 * wC.y;
  float v1 = z0 * wA.y + z1 * wB.x + z2 * wB.w + z3 * wC.z;
  float v2 = z0 * wA.z + z1 * wB.y + z2 * wC.x + z3 * wC.w;
#pragma unroll
  for (int off = 8; off > 0; off >>= 1) {  // stays within each 16-lane group
    v0 += __shfl_xor(v0, off);
    v1 += __shfl_xor(v1, off);
    v2 += __shfl_xor(v2, off);
  }
  if (sl == 0) h2[node] = make_float4(v0 * dc, v1 * dc, v2 * dc, dc);
}

// ---- fused layer-2 aggregation + mean pool: 2 threads/node, float4 gather of h2s ----
extern "C" __global__ __launch_bounds__(256) void k_agg2pool(
    const float4* __restrict__ h2, const int* __restrict__ starts, const int* __restrict__ cnt,
    const int* __restrict__ nbr, float* __restrict__ out) {
  int gid = blockIdx.x * 256 + threadIdx.x;
  int n = gid >> 1;
  int par = gid & 1;
  int start = starts[n], deg = cnt[n], end = start + deg;
  float4 hs = h2[n];  // self term (h2s[n]) + dis[n] in .w
  float s0 = 0.f, s1 = 0.f, s2 = 0.f;
  if (par == 0) { s0 = hs.x; s1 = hs.y; s2 = hs.z; }
  int e = start + par;
  for (; e + 2 < end; e += 4) {  // this thread's edges: par, par+2, ... (2-deep ILP)
    int n0 = nbr[e], n1 = nbr[e + 2];
    float4 h0 = h2[n0], h1 = h2[n1];
    s0 += h0.x + h1.x;
    s1 += h0.y + h1.y;
    s2 += h0.z + h1.z;
  }
  for (; e < end; e += 2) {
    float4 h0 = h2[nbr[e]];
    s0 += h0.x;
    s1 += h0.y;
    s2 += h0.z;
  }
  // fold odd partner into even, scale by dis[n]
  s0 += __shfl_xor(s0, 1);
  s1 += __shfl_xor(s1, 1);
  s2 += __shfl_xor(s2, 1);
  float dn = hs.w;
  if (par) { s0 = 0.f; s1 = 0.f; s2 = 0.f; }
  else { s0 *= dn; s1 *= dn; s2 *= dn; }
  __shared__ float red[3][256];
  int t = threadIdx.x;
  red[0][t] = s0; red[1][t] = s1; red[2][t] = s2;
  __syncthreads();
  for (int off = 128; off > 0; off >>= 1) {
    if (t < off) {
      red[0][t] += red[0][t + off];
      red[1][t] += red[1][t + off];
      red[2][t] += red[2][t + off];
    }
    __syncthreads();
  }
  if (t == 0) {
    int g = blockIdx.x >> 5;  // 32 blocks of 128 nodes per 4096-node graph
    const float inv = 1.0f / (float)NPG;
    atomicAdd(&out[g * 3 + 0], red[0][0] * inv);
    atomicAdd(&out[g * 3 + 1], red[1][0] * inv);
    atomicAdd(&out[g * 3 + 2], red[2][0] * inv);
  }
}

extern "C" void kernel_launch(void* const* d_in, const int* in_sizes, int n_in,
                              void* d_out, int out_size, void* d_ws, size_t ws_size,
                              hipStream_t stream) {
  const float* x  = (const float*)d_in[0];
  const int*   ei = (const int*)d_in[1];
  const float* W1 = (const float*)d_in[3];
  const float* b1 = (const float*)d_in[4];
  const float* W2 = (const float*)d_in[5];
  const float* b2 = (const float*)d_in[6];
  const int* row = ei;
  const int* col = ei + NE;
  float* out = (float*)d_out;

  // workspace layout (byte offsets)
  char* ws = (char*)d_ws;
  int*   cnt     = (int*)(ws + 0);             // 512 KB
  float* dis     = (float*)(ws + (1u << 19));  // 512 KB
  int*   starts  = (int*)(ws + (2u << 19));    // 512 KB
  int*   bcursor = (int*)(ws + (3u << 19));    // 2 KB (counts; zeroed each call)
  int*   ebuf    = (int*)(ws + (4u << 19));    // 512*2560*4 = 5.24 MB
  int*   nbr     = (int*)(ws + (1u << 23));    // padded CSR, 5.24 MB
  unsigned char* h1f = (unsigned char*)(ws + (1u << 24));  // fp8, 8 MB
  float4* h2     = (float4*)(ws + (1u << 25) + 4096u);     // 2 MB

  hipMemsetAsync(bcursor, 0, NB * sizeof(int), stream);
  k_bscatter<<<NE / 4096, 256, 0, stream>>>(row, col, bcursor, ebuf);
  k_blocal<<<NB, 256, 0, stream>>>(ebuf, bcursor, cnt, dis, starts, nbr);
  k_gemm1s<<<NN / 256, 256, 0, stream>>>(x, W1, h1f, b2, out);
  k_agg1f<<<NN / 16, 256, 0, stream>>>(h1f, starts, cnt, nbr, dis, b1, W2, h2);
  k_agg2pool<<<NN * 2 / 256, 256, 0, stream>>>(h2, starts, cnt, nbr, out);
}

// Round 17
// 91.663 us; speedup vs baseline: 1.0451x; 1.0451x over previous
//
#include <hip/hip_runtime.h>

#define NN 131072
#define NE 1048576
#define DD 64
#define NG 32
#define NPG 4096
#define NB 512      // buckets (c>>8), 256 nodes each
#define CAPB 2560   // padded bucket capacity (E=2048, +11 sigma)

typedef __attribute__((ext_vector_type(2))) float f32x2;

// ---- bucket scatter: 512 blocks x 2048 edges, 512 threads x 4 edges (16 waves/CU) ----
extern "C" __global__ __launch_bounds__(512) void k_bscatter(
    const int* __restrict__ row, const int* __restrict__ col, int* __restrict__ bcursor,
    int* __restrict__ ebuf) {
  __shared__ int sh[NB];   // local histogram
  __shared__ int sb[NB];   // global base per bin
  int t = threadIdx.x;     // 0..511
  sh[t] = 0;
  __syncthreads();
  int base = blockIdx.x * 2048 + t * 4;
  int4 c = *reinterpret_cast<const int4*>(col + base);
  int cols[4] = {c.x, c.y, c.z, c.w};
  int lr[4];
#pragma unroll
  for (int k = 0; k < 4; ++k) lr[k] = atomicAdd(&sh[cols[k] >> 8], 1);
  __syncthreads();
  int h0 = sh[t];
  sb[t] = t * CAPB + (h0 ? atomicAdd(&bcursor[t], h0) : 0);
  __syncthreads();
  int4 r = *reinterpret_cast<const int4*>(row + base);
  int rows[4] = {r.x, r.y, r.z, r.w};
#pragma unroll
  for (int k = 0; k < 4; ++k) {
    int key = cols[k] >> 8;
    int pos = sb[key] + lr[k];
    if (pos < (key + 1) * CAPB)  // guard never hits
      ebuf[pos] = (rows[k] << 8) | (cols[k] & 255);
  }
}

// ---- per-bucket: histogram -> cnt/dis/starts, then LDS-cursor scatter of nbr ----
extern "C" __global__ __launch_bounds__(256) void k_blocal(
    const int* __restrict__ ebuf, const int* __restrict__ bcursor, int* __restrict__ cnt,
    float* __restrict__ dis, int* __restrict__ starts, int* __restrict__ nbr) {
  __shared__ int sh[256];  // per-node histogram
  __shared__ int sx[256];  // scan workspace, then cursor
  int b = blockIdx.x, t = threadIdx.x;
  int bs = b * CAPB;
  int n_e = bcursor[b];
  if (n_e > CAPB) n_e = CAPB;
  sh[t] = 0;
  __syncthreads();
  for (int i = t; i < n_e; i += 256) atomicAdd(&sh[ebuf[bs + i] & 255], 1);
  __syncthreads();
  int v = sh[t];
  sx[t] = v;
  __syncthreads();
  for (int off = 1; off < 256; off <<= 1) {
    int u = (t >= off) ? sx[t - off] : 0;
    __syncthreads();
    sx[t] += u;
    __syncthreads();
  }
  int st = bs + sx[t] - v;  // global start (padded layout)
  int node = b * 256 + t;
  cnt[node] = v;
  dis[node] = rsqrtf((float)v + 1.0f);
  starts[node] = st;
  sx[t] = st;  // becomes cursor
  __syncthreads();
  for (int i = t; i < n_e; i += 256) {
    int ed = ebuf[bs + i];
    int pos = atomicAdd(&sx[ed & 255], 1);
    nbr[pos] = ed >> 8;
  }
}

// ---- GEMM1: h1s = fp8(dis .* (x @ W1)) (OCP e4m3, HW pack), 2 rows/thread ----
// block 0 extras: zero row NN (gather pad target) + seed out with b2.
extern "C" __global__ __launch_bounds__(256) void k_gemm1s(
    const float* __restrict__ x, const float* __restrict__ W1, const float* __restrict__ dis,
    unsigned char* __restrict__ h1f, const float* __restrict__ b2, float* __restrict__ out) {
  __shared__ float4 wl[DD * 16];  // W1 as [k][j4], 16 KB
  int t = threadIdx.x;
  if (blockIdx.x == 0) {
    if (t < 16) reinterpret_cast<unsigned int*>(h1f + (size_t)NN * 64)[t] = 0u;
    if (t < NG * 3) out[t] = b2[t % 3];
  }
  for (int i = t; i < DD * 16; i += 256) wl[i] = reinterpret_cast<const float4*>(W1)[i];
  __syncthreads();
  int jc = t & 3;   // column chunk: cols [16*jc, 16*jc+16)
  int rg = t >> 2;  // row group 0..63, 2 rows each
  size_t rbase = (size_t)blockIdx.x * 128 + (size_t)rg * 2;
  const float4* xp = reinterpret_cast<const float4*>(x + rbase * DD);
  float2 sc = *reinterpret_cast<const float2*>(dis + rbase);  // dis for both rows
  float4 acc[2][4];
#pragma unroll
  for (int r = 0; r < 2; ++r)
#pragma unroll
    for (int j = 0; j < 4; ++j) acc[r][j] = make_float4(0.f, 0.f, 0.f, 0.f);
#pragma unroll 2
  for (int kk = 0; kk < 16; ++kk) {
    float4 a0 = xp[kk];
    float4 a1 = xp[16 + kk];
#pragma unroll
    for (int j = 0; j < 4; ++j) {
      float4 w0 = wl[(4 * kk + 0) * 16 + jc * 4 + j];
      float4 w1 = wl[(4 * kk + 1) * 16 + jc * 4 + j];
      float4 w2 = wl[(4 * kk + 2) * 16 + jc * 4 + j];
      float4 w3 = wl[(4 * kk + 3) * 16 + jc * 4 + j];
      acc[0][j].x += a0.x * w0.x + a0.y * w1.x + a0.z * w2.x + a0.w * w3.x;
      acc[0][j].y += a0.x * w0.y + a0.y * w1.y + a0.z * w2.y + a0.w * w3.y;
      acc[0][j].z += a0.x * w0.z + a0.y * w1.z + a0.z * w2.z + a0.w * w3.z;
      acc[0][j].w += a0.x * w0.w + a0.y * w1.w + a0.z * w2.w + a0.w * w3.w;
      acc[1][j].x += a1.x * w0.x + a1.y * w1.x + a1.z * w2.x + a1.w * w3.x;
      acc[1][j].y += a1.x * w0.y + a1.y * w1.y + a1.z * w2.y + a1.w * w3.y;
      acc[1][j].z += a1.x * w0.z + a1.y * w1.z + a1.z * w2.z + a1.w * w3.z;
      acc[1][j].w += a1.x * w0.w + a1.y * w1.w + a1.z * w2.w + a1.w * w3.w;
    }
  }
#pragma unroll
  for (int r = 0; r < 2; ++r) {
    float s = r ? sc.y : sc.x;
    unsigned int d[4];
#pragma unroll
    for (int j = 0; j < 4; ++j) {
      float4 a = acc[r][j];
      int dj = __builtin_amdgcn_cvt_pk_fp8_f32(a.x * s, a.y * s, 0, false);
      dj = __builtin_amdgcn_cvt_pk_fp8_f32(a.z * s, a.w * s, dj, true);
      d[j] = (unsigned int)dj;
    }
    *reinterpret_cast<uint4*>(h1f + (rbase + r) * 64 + jc * 16) =
        make_uint4(d[0], d[1], d[2], d[3]);
  }
}

// ---- fused agg1: 4 nodes/wave (16 lanes each, 4 dims/lane), weightless fp8 gather, ILP 8 ----
extern "C" __global__ __launch_bounds__(256) void k_agg1f(
    const unsigned char* __restrict__ h1f, const int* __restrict__ starts,
    const int* __restrict__ cnt, const int* __restrict__ nbr, const float* __restrict__ dis,
    const float* __restrict__ b1, const float* __restrict__ W2, float4* __restrict__ h2) {
  __shared__ int sed[4][4][16];  // per wave, per node-group: neighbor index; 1 KB
  int lane = threadIdx.x & 63;
  int wid = threadIdx.x >> 6;
  int g = lane >> 4;   // node group within wave
  int sl = lane & 15;  // slot index; also owns dims [4sl, 4sl+4)
  int node = blockIdx.x * 16 + wid * 4 + g;
  int start = starts[node];
  int deg = cnt[node];
  float dc = dis[node];
  // stage 16 slots: edges, self at slot deg (if deg<16), pads -> zero row NN
  int nb = NN;
  if (sl < deg) nb = nbr[start + sl];
  else if (sl == deg) nb = node;
  sed[wid][g][sl] = nb;
  int m = (deg < 16) ? (deg + 1) : 16;
  int mw = max(m, __shfl_xor(m, 16));  // max over the 4 groups of this wave
  mw = max(mw, __shfl_xor(mw, 32));
  int mw8 = (mw + 7) & ~7;  // 8 or 16; all 16 slots initialized, pads are zero row
  asm volatile("s_waitcnt lgkmcnt(0)" ::: "memory");  // sed is wave-private
  __builtin_amdgcn_sched_barrier(0);
  const unsigned int* h1u = reinterpret_cast<const unsigned int*>(h1f);  // row = 16 dwords
  const int* sp = sed[wid][g];
  float a0 = 0.f, a1 = 0.f, a2 = 0.f, a3 = 0.f;
  for (int e = 0; e < mw8; e += 8) {  // 8 independent gather chains; pads add zero
    int n0 = sp[e + 0], n1 = sp[e + 1], n2 = sp[e + 2], n3 = sp[e + 3];
    int n4 = sp[e + 4], n5 = sp[e + 5], n6 = sp[e + 6], n7 = sp[e + 7];
    unsigned int u0 = h1u[(size_t)n0 * 16 + sl];
    unsigned int u1 = h1u[(size_t)n1 * 16 + sl];
    unsigned int u2 = h1u[(size_t)n2 * 16 + sl];
    unsigned int u3 = h1u[(size_t)n3 * 16 + sl];
    unsigned int u4 = h1u[(size_t)n4 * 16 + sl];
    unsigned int u5 = h1u[(size_t)n5 * 16 + sl];
    unsigned int u6 = h1u[(size_t)n6 * 16 + sl];
    unsigned int u7 = h1u[(size_t)n7 * 16 + sl];
    f32x2 p0 = __builtin_amdgcn_cvt_pk_f32_fp8(u0, false);
    f32x2 q0 = __builtin_amdgcn_cvt_pk_f32_fp8(u0, true);
    f32x2 p1 = __builtin_amdgcn_cvt_pk_f32_fp8(u1, false);
    f32x2 q1 = __builtin_amdgcn_cvt_pk_f32_fp8(u1, true);
    f32x2 p2 = __builtin_amdgcn_cvt_pk_f32_fp8(u2, false);
    f32x2 q2 = __builtin_amdgcn_cvt_pk_f32_fp8(u2, true);
    f32x2 p3 = __builtin_amdgcn_cvt_pk_f32_fp8(u3, false);
    f32x2 q3 = __builtin_amdgcn_cvt_pk_f32_fp8(u3, true);
    f32x2 p4 = __builtin_amdgcn_cvt_pk_f32_fp8(u4, false);
    f32x2 q4 = __builtin_amdgcn_cvt_pk_f32_fp8(u4, true);
    f32x2 p5 = __builtin_amdgcn_cvt_pk_f32_fp8(u5, false);
    f32x2 q5 = __builtin_amdgcn_cvt_pk_f32_fp8(u5, true);
    f32x2 p6 = __builtin_amdgcn_cvt_pk_f32_fp8(u6, false);
    f32x2 q6 = __builtin_amdgcn_cvt_pk_f32_fp8(u6, true);
    f32x2 p7 = __builtin_amdgcn_cvt_pk_f32_fp8(u7, false);
    f32x2 q7 = __builtin_amdgcn_cvt_pk_f32_fp8(u7, true);
    a0 += (p0.x + p1.x) + (p2.x + p3.x) + (p4.x + p5.x) + (p6.x + p7.x);
    a1 += (p0.y + p1.y) + (p2.y + p3.y) + (p4.y + p5.y) + (p6.y + p7.y);
    a2 += (q0.x + q1.x) + (q2.x + q3.x) + (q4.x + q5.x) + (q6.x + q7.x);
    a3 += (q0.y + q1.y) + (q2.y + q3.y) + (q4.y + q5.y) + (q6.y + q7.y);
  }
  if (deg >= 16) {  // rare tail (~1% of nodes): remaining edges + self
    for (int eo = 16; eo < deg; ++eo) {
      int r = nbr[start + eo];
      unsigned int u = h1u[(size_t)r * 16 + sl];
      f32x2 p = __builtin_amdgcn_cvt_pk_f32_fp8(u, false);
      f32x2 q = __builtin_amdgcn_cvt_pk_f32_fp8(u, true);
      a0 += p.x; a1 += p.y; a2 += q.x; a3 += q.y;
    }
    unsigned int u = h1u[(size_t)node * 16 + sl];
    f32x2 p = __builtin_amdgcn_cvt_pk_f32_fp8(u, false);
    f32x2 q = __builtin_amdgcn_cvt_pk_f32_fp8(u, true);
    a0 += p.x; a1 += p.y; a2 += q.x; a3 += q.y;
  }
  // layer2: z = relu(dc*a + b1); store h2s = dc * (z @ W2), dis in .w
  float4 bb = *reinterpret_cast<const float4*>(b1 + 4 * sl);
  float z0 = fmaxf(fmaf(dc, a0, bb.x), 0.f);
  float z1 = fmaxf(fmaf(dc, a1, bb.y), 0.f);
  float z2 = fmaxf(fmaf(dc, a2, bb.z), 0.f);
  float z3 = fmaxf(fmaf(dc, a3, bb.w), 0.f);
  const float4* wp = reinterpret_cast<const float4*>(W2 + 12 * sl);
  float4 wA = wp[0];  // W2[4sl][0..2], W2[4sl+1][0]
  float4 wB = wp[1];  // W2[4sl+1][1..2], W2[4sl+2][0..1]
  float4 wC = wp[2];  // W2[4sl+2][2], W2[4sl+3][0..2]
  float v0 = z0 * wA.x + z1 * wA.w + z2 * wB.z + z3 * wC.y;
  float v1 = z0 * wA.y + z1 * wB.x + z2 * wB.w + z3 * wC.z;
  float v2 = z0 * wA.z + z1 * wB.y + z2 * wC.x + z3 * wC.w;
#pragma unroll
  for (int off = 8; off > 0; off >>= 1) {  // stays within each 16-lane group
    v0 += __shfl_xor(v0, off);
    v1 += __shfl_xor(v1, off);
    v2 += __shfl_xor(v2, off);
  }
  if (sl == 0) h2[node] = make_float4(v0 * dc, v1 * dc, v2 * dc, dc);
}

// ---- fused layer-2 aggregation + mean pool: weightless float4 gather of h2s, ILP 4 ----
extern "C" __global__ __launch_bounds__(256) void k_agg2pool(
    const float4* __restrict__ h2, const int* __restrict__ starts, const int* __restrict__ cnt,
    const int* __restrict__ nbr, float* __restrict__ out) {
  int n = blockIdx.x * 256 + threadIdx.x;
  int start = starts[n], deg = cnt[n], end = start + deg;
  float4 hs = h2[n];  // self term (h2s[n]) + dis[n] in .w
  float s0 = hs.x, s1 = hs.y, s2 = hs.z;
  int e = start;
  for (; e + 4 <= end; e += 4) {
    int n0 = nbr[e], n1 = nbr[e + 1], n2 = nbr[e + 2], n3 = nbr[e + 3];
    float4 h0 = h2[n0], h1 = h2[n1], g2 = h2[n2], g3 = h2[n3];
    s0 += (h0.x + h1.x) + (g2.x + g3.x);
    s1 += (h0.y + h1.y) + (g2.y + g3.y);
    s2 += (h0.z + h1.z) + (g2.z + g3.z);
  }
  for (; e < end; ++e) {
    float4 h0 = h2[nbr[e]];
    s0 += h0.x;
    s1 += h0.y;
    s2 += h0.z;
  }
  float dn = hs.w;
  s0 *= dn; s1 *= dn; s2 *= dn;
  __shared__ float red[3][256];
  int t = threadIdx.x;
  red[0][t] = s0; red[1][t] = s1; red[2][t] = s2;
  __syncthreads();
  for (int off = 128; off > 0; off >>= 1) {
    if (t < off) {
      red[0][t] += red[0][t + off];
      red[1][t] += red[1][t + off];
      red[2][t] += red[2][t + off];
    }
    __syncthreads();
  }
  if (t == 0) {
    int g = blockIdx.x >> 4;  // 16 blocks of 256 nodes per 4096-node graph
    const float inv = 1.0f / (float)NPG;
    atomicAdd(&out[g * 3 + 0], red[0][0] * inv);
    atomicAdd(&out[g * 3 + 1], red[1][0] * inv);
    atomicAdd(&out[g * 3 + 2], red[2][0] * inv);
  }
}

extern "C" void kernel_launch(void* const* d_in, const int* in_sizes, int n_in,
                              void* d_out, int out_size, void* d_ws, size_t ws_size,
                              hipStream_t stream) {
  const float* x  = (const float*)d_in[0];
  const int*   ei = (const int*)d_in[1];
  const float* W1 = (const float*)d_in[3];
  const float* b1 = (const float*)d_in[4];
  const float* W2 = (const float*)d_in[5];
  const float* b2 = (const float*)d_in[6];
  const int* row = ei;
  const int* col = ei + NE;
  float* out = (float*)d_out;

  // workspace layout (byte offsets)
  char* ws = (char*)d_ws;
  int*   cnt     = (int*)(ws + 0);             // 512 KB
  float* dis     = (float*)(ws + (1u << 19));  // 512 KB
  int*   starts  = (int*)(ws + (2u << 19));    // 512 KB
  int*   bcursor = (int*)(ws + (3u << 19));    // 2 KB (counts; zeroed each call)
  int*   ebuf    = (int*)(ws + (4u << 19));    // 512*2560*4 = 5.24 MB
  int*   nbr     = (int*)(ws + (1u << 23));    // padded CSR, 5.24 MB
  unsigned char* h1f = (unsigned char*)(ws + (1u << 24));  // fp8, 8 MB + 64 B zero row
  float4* h2     = (float4*)(ws + (1u << 25) + 4096u);     // 2 MB

  hipMemsetAsync(bcursor, 0, NB * sizeof(int), stream);
  k_bscatter<<<NE / 2048, 512, 0, stream>>>(row, col, bcursor, ebuf);
  k_blocal<<<NB, 256, 0, stream>>>(ebuf, bcursor, cnt, dis, starts, nbr);
  k_gemm1s<<<NN / 128, 256, 0, stream>>>(x, W1, dis, h1f, b2, out);
  k_agg1f<<<NN / 16, 256, 0, stream>>>(h1f, starts, cnt, nbr, dis, b1, W2, h2);
  k_agg2pool<<<NN / 256, 256, 0, stream>>>(h2, starts, cnt, nbr, out);
}